// Round 4
// baseline (108.772 us; speedup 1.0000x reference)
//
#include <hip/hip_runtime.h>
#include <hip/hip_bf16.h>

typedef __attribute__((ext_vector_type(8))) short short8;
typedef __attribute__((ext_vector_type(4))) float floatx4;

#define HW_TOK 4096
#define KLEN 308
#define KPAD 320
#define DH 64
#define INNER 512
#define KSTR 72      // Klds row stride (ushort): 64 + 8 pad
#define VSTR 328     // Vt row stride (ushort): 320 + 8 pad
#define PSTR 72      // P scratch row stride (ushort)
#define NWAVE 8

// round-to-nearest-even f32 -> bf16
__device__ __forceinline__ unsigned short f2bf(float f) {
    union { float f; unsigned u; } x; x.f = f;
    unsigned u = x.u;
    return (unsigned short)((u + 0x7FFFu + ((u >> 16) & 1u)) >> 16);
}

__global__ __launch_bounds__(512, 2)   // 2 waves/EU -> VGPR cap 256, no spills
void dd_attn_kernel(const float* __restrict__ q,
                    const float* __restrict__ k,
                    const float* __restrict__ v,
                    const float* __restrict__ dd,
                    float* __restrict__ out) {
    __shared__ unsigned short Klds[KPAD][KSTR];          // 46080 B
    __shared__ unsigned short Vt[DH][VSTR];              // 41984 B
    __shared__ unsigned short Pw[NWAVE][2][16][PSTR];    // 36864 B (per-wave dbuf)
    __shared__ float rscale_s[4];

    const int tid  = threadIdx.x;
    const int lane = tid & 63;
    const int wave = tid >> 6;
    const int quad = lane >> 4;
    const int l15  = lane & 15;

    const int bid = blockIdx.x;
    const int bh  = bid >> 4;      // 0..15
    const int grp = bid & 15;      // 16 q-tile-groups per (b,h)
    const int b = bh >> 3;
    const int h = bh & 7;

    const float* qp = q + (size_t)b * HW_TOK * INNER + h * DH;
    const float* kp = k + (size_t)b * KLEN * INNER + h * DH;
    const float* vp = v + (size_t)b * KLEN * INNER + h * DH;
    float* op = out + (size_t)b * HW_TOK * INNER + h * DH;

    // ---- stage K bf16 (zero-pad rows 308..319) ----
    for (int e = tid; e < KPAD * 32; e += 512) {
        int row = e >> 5, d2 = e & 31;
        float2 f = make_float2(0.f, 0.f);
        if (row < KLEN) f = *(const float2*)(kp + (size_t)row * INNER + 2 * d2);
        *(unsigned*)&Klds[row][2 * d2] = ((unsigned)f2bf(f.y) << 16) | f2bf(f.x);
    }
    // ---- stage V^T bf16 ----
    for (int e = tid; e < KLEN * 32; e += 512) {
        int col = e >> 5, d2 = e & 31;
        float2 f = *(const float2*)(vp + (size_t)col * INNER + 2 * d2);
        Vt[2 * d2][col]     = f2bf(f.x);
        Vt[2 * d2 + 1][col] = f2bf(f.y);
    }
    for (int e = tid; e < DH * 12; e += 512) {   // zero pad cols 308..319
        int d = e / 12, c = e % 12;
        Vt[d][KLEN + c] = 0;
    }
    // ---- region scales ----
    if (wave < 4) {
        float p = 0.f;
        #pragma unroll
        for (int i = 0; i < 16; ++i) p += dd[wave * 1024 + lane + 64 * i];
        #pragma unroll
        for (int off = 32; off >= 1; off >>= 1) p += __shfl_xor(p, off);
        if (lane == 0) rscale_s[wave] = 4096.0f / (4.0f * p);
    }
    __syncthreads();   // the ONLY barrier

    const float rsv[4] = {rscale_s[0], rscale_s[1], rscale_s[2], rscale_s[3]};

    for (int it = 0; it < 2; ++it) {
        const int q0 = (grp * 16 + wave * 2 + it) * 16;

        // ---- Q A-fragments straight from global (f32 -> bf16) ----
        const float* qr = qp + (size_t)(q0 + l15) * INNER + quad * 8;
        float4 f0 = *(const float4*)(qr);
        float4 f1 = *(const float4*)(qr + 4);
        float4 f2 = *(const float4*)(qr + 32);
        float4 f3 = *(const float4*)(qr + 36);
        short8 a0, a1;
        a0[0]=(short)f2bf(f0.x); a0[1]=(short)f2bf(f0.y); a0[2]=(short)f2bf(f0.z); a0[3]=(short)f2bf(f0.w);
        a0[4]=(short)f2bf(f1.x); a0[5]=(short)f2bf(f1.y); a0[6]=(short)f2bf(f1.z); a0[7]=(short)f2bf(f1.w);
        a1[0]=(short)f2bf(f2.x); a1[1]=(short)f2bf(f2.y); a1[2]=(short)f2bf(f2.z); a1[3]=(short)f2bf(f2.w);
        a1[4]=(short)f2bf(f3.x); a1[5]=(short)f2bf(f3.y); a1[6]=(short)f2bf(f3.z); a1[7]=(short)f2bf(f3.w);

        // ---- QK^T: 20 n-tiles, all independent ----
        floatx4 acc[20];
        #pragma unroll
        for (int nt = 0; nt < 20; ++nt) {
            int col = nt * 16 + l15;
            short8 b0 = *(const short8*)&Klds[col][quad * 8];
            short8 b1 = *(const short8*)&Klds[col][32 + quad * 8];
            floatx4 c = {0.f, 0.f, 0.f, 0.f};
            c = __builtin_amdgcn_mfma_f32_16x16x32_bf16(a0, b0, c, 0, 0, 0);
            c = __builtin_amdgcn_mfma_f32_16x16x32_bf16(a1, b1, c, 0, 0, 0);
            acc[nt] = c;
        }

        // ---- per-row/region coefficients (mask bit * scale, or -1 = masked) ----
        float coef[4][4];
        #pragma unroll
        for (int r = 0; r < 4; ++r) {
            int qrow = q0 + quad * 4 + r;
            int mi = (qrow >> 7) * 32 + ((qrow & 63) >> 1);   // nearest-exact 64->32
            #pragma unroll
            for (int rg = 0; rg < 4; ++rg) {
                float mv = dd[rg * 1024 + mi];
                coef[r][rg] = (mv > 0.5f) ? 0.125f * rsv[rg] : -1.0f;
            }
        }

        // ---- mask + scale + row-max (in C-layout registers) ----
        float mx[4] = {-INFINITY, -INFINITY, -INFINITY, -INFINITY};
        #pragma unroll
        for (int nt = 0; nt < 20; ++nt) {
            #pragma unroll
            for (int r = 0; r < 4; ++r) {
                float c;
                if      (nt <  4) c = coef[r][0];
                else if (nt == 4) c = (l15 < 13) ? coef[r][0] : coef[r][1];
                else if (nt <  9) c = coef[r][1];
                else if (nt == 9) c = (l15 < 10) ? coef[r][1] : coef[r][2];
                else if (nt < 14) c = coef[r][2];
                else if (nt ==14) c = (l15 <  7) ? coef[r][2] : coef[r][3];
                else if (nt < 19) c = coef[r][3];
                else              c = (l15 <  4) ? coef[r][3] : -1.0f;
                float sv = (c > 0.f) ? acc[nt][r] * c : -INFINITY;
                acc[nt][r] = sv;
                mx[r] = fmaxf(mx[r], sv);
            }
        }
        #pragma unroll
        for (int off = 1; off < 16; off <<= 1) {
            #pragma unroll
            for (int r = 0; r < 4; ++r) mx[r] = fmaxf(mx[r], __shfl_xor(mx[r], off));
        }

        // ---- exp + row-sum ----
        float sm[4] = {0.f, 0.f, 0.f, 0.f};
        #pragma unroll
        for (int nt = 0; nt < 20; ++nt) {
            #pragma unroll
            for (int r = 0; r < 4; ++r) {
                float p = __expf(acc[nt][r] - mx[r]);   // exp(-inf)=0 for masked
                acc[nt][r] = p;
                sm[r] += p;
            }
        }
        #pragma unroll
        for (int off = 1; off < 16; off <<= 1) {
            #pragma unroll
            for (int r = 0; r < 4; ++r) sm[r] += __shfl_xor(sm[r], off);
        }
        float inv[4];
        #pragma unroll
        for (int r = 0; r < 4; ++r) inv[r] = 1.0f / sm[r];

        // ---- PV: 5 chunks of 64 cols; P transposed via per-wave LDS scratch ----
        floatx4 oacc[4] = {{0.f,0.f,0.f,0.f},{0.f,0.f,0.f,0.f},{0.f,0.f,0.f,0.f},{0.f,0.f,0.f,0.f}};
        #pragma unroll
        for (int c5 = 0; c5 < 5; ++c5) {
            const int buf = c5 & 1;
            #pragma unroll
            for (int nt2 = 0; nt2 < 4; ++nt2) {
                int nt = c5 * 4 + nt2;
                #pragma unroll
                for (int r = 0; r < 4; ++r)
                    Pw[wave][buf][quad * 4 + r][nt2 * 16 + l15] = f2bf(acc[nt][r]);
            }
            #pragma unroll
            for (int ks = 0; ks < 2; ++ks) {
                short8 pa = *(const short8*)&Pw[wave][buf][l15][ks * 32 + quad * 8];
                #pragma unroll
                for (int n = 0; n < 4; ++n) {
                    short8 bv = *(const short8*)&Vt[n * 16 + l15][c5 * 64 + ks * 32 + quad * 8];
                    oacc[n] = __builtin_amdgcn_mfma_f32_16x16x32_bf16(pa, bv, oacc[n], 0, 0, 0);
                }
            }
        }

        // ---- normalize + store (C-layout, direct) ----
        #pragma unroll
        for (int n = 0; n < 4; ++n) {
            #pragma unroll
            for (int r = 0; r < 4; ++r) {
                op[(size_t)(q0 + quad * 4 + r) * INNER + n * 16 + l15] = oacc[n][r] * inv[r];
            }
        }
    }
}

extern "C" void kernel_launch(void* const* d_in, const int* in_sizes, int n_in,
                              void* d_out, int out_size, void* d_ws, size_t ws_size,
                              hipStream_t stream) {
    const float* q  = (const float*)d_in[0];
    const float* k  = (const float*)d_in[1];
    const float* v  = (const float*)d_in[2];
    const float* dd = (const float*)d_in[3];
    float* out = (float*)d_out;
    dd_attn_kernel<<<dim3(256), dim3(512), 0, stream>>>(q, k, v, dd, out);
}

// Round 5
// 107.672 us; speedup vs baseline: 1.0102x; 1.0102x over previous
//
#include <hip/hip_runtime.h>
#include <hip/hip_bf16.h>

typedef __attribute__((ext_vector_type(8))) short short8;
typedef __attribute__((ext_vector_type(4))) float floatx4;

#define HW_TOK 4096
#define KLEN 308
#define KPAD 320
#define DH 64
#define INNER 512
#define KSTR 72      // Klds row stride (ushort): 64 + 8 pad
#define VSTR 328     // Vt row stride (ushort): 320 + 8 pad
#define PSTR 72      // P scratch row stride (ushort)
#define NWAVE 8

// round-to-nearest-even f32 -> bf16
__device__ __forceinline__ unsigned short f2bf(float f) {
    union { float f; unsigned u; } x; x.f = f;
    unsigned u = x.u;
    return (unsigned short)((u + 0x7FFFu + ((u >> 16) & 1u)) >> 16);
}

// launch_bounds 2nd arg behaves as min BLOCKS/CU on this toolchain (R4 evidence:
// (512,2) -> 128-VGPR cap). (512,1) -> 1 block/CU -> 2 waves/EU -> 256-VGPR cap,
// which is also the HW-implied cap for a resident 512-thread block. No spills.
__global__ __launch_bounds__(512, 1)
void dd_attn_kernel(const float* __restrict__ q,
                    const float* __restrict__ k,
                    const float* __restrict__ v,
                    const float* __restrict__ dd,
                    float* __restrict__ out) {
    __shared__ unsigned short Klds[KPAD][KSTR];          // 46080 B
    __shared__ unsigned short Vt[DH][VSTR];              // 41984 B
    __shared__ unsigned short Pw[NWAVE][2][16][PSTR];    // 36864 B (per-wave dbuf)
    __shared__ float rscale_s[4];

    const int tid  = threadIdx.x;
    const int lane = tid & 63;
    const int wave = tid >> 6;
    const int quad = lane >> 4;
    const int l15  = lane & 15;

    const int bid = blockIdx.x;
    const int bh  = bid >> 4;      // 0..15
    const int grp = bid & 15;      // 16 q-tile-groups per (b,h)
    const int b = bh >> 3;
    const int h = bh & 7;

    const float* qp = q + (size_t)b * HW_TOK * INNER + h * DH;
    const float* kp = k + (size_t)b * KLEN * INNER + h * DH;
    const float* vp = v + (size_t)b * KLEN * INNER + h * DH;
    float* op = out + (size_t)b * HW_TOK * INNER + h * DH;

    // ---- stage K bf16 (zero-pad rows 308..319) ----
    for (int e = tid; e < KPAD * 32; e += 512) {
        int row = e >> 5, d2 = e & 31;
        float2 f = make_float2(0.f, 0.f);
        if (row < KLEN) f = *(const float2*)(kp + (size_t)row * INNER + 2 * d2);
        *(unsigned*)&Klds[row][2 * d2] = ((unsigned)f2bf(f.y) << 16) | f2bf(f.x);
    }
    // ---- stage V^T bf16 ----
    for (int e = tid; e < KLEN * 32; e += 512) {
        int col = e >> 5, d2 = e & 31;
        float2 f = *(const float2*)(vp + (size_t)col * INNER + 2 * d2);
        Vt[2 * d2][col]     = f2bf(f.x);
        Vt[2 * d2 + 1][col] = f2bf(f.y);
    }
    for (int e = tid; e < DH * 12; e += 512) {   // zero pad cols 308..319
        int d = e / 12, c = e % 12;
        Vt[d][KLEN + c] = 0;
    }
    // ---- region scales ----
    if (wave < 4) {
        float p = 0.f;
        #pragma unroll
        for (int i = 0; i < 16; ++i) p += dd[wave * 1024 + lane + 64 * i];
        #pragma unroll
        for (int off = 32; off >= 1; off >>= 1) p += __shfl_xor(p, off);
        if (lane == 0) rscale_s[wave] = 4096.0f / (4.0f * p);
    }
    __syncthreads();   // the ONLY barrier

    const float rsv[4] = {rscale_s[0], rscale_s[1], rscale_s[2], rscale_s[3]};

    for (int it = 0; it < 2; ++it) {
        const int q0 = (grp * 16 + wave * 2 + it) * 16;

        // ---- Q A-fragments straight from global (f32 -> bf16) ----
        const float* qr = qp + (size_t)(q0 + l15) * INNER + quad * 8;
        float4 f0 = *(const float4*)(qr);
        float4 f1 = *(const float4*)(qr + 4);
        float4 f2 = *(const float4*)(qr + 32);
        float4 f3 = *(const float4*)(qr + 36);
        short8 a0, a1;
        a0[0]=(short)f2bf(f0.x); a0[1]=(short)f2bf(f0.y); a0[2]=(short)f2bf(f0.z); a0[3]=(short)f2bf(f0.w);
        a0[4]=(short)f2bf(f1.x); a0[5]=(short)f2bf(f1.y); a0[6]=(short)f2bf(f1.z); a0[7]=(short)f2bf(f1.w);
        a1[0]=(short)f2bf(f2.x); a1[1]=(short)f2bf(f2.y); a1[2]=(short)f2bf(f2.z); a1[3]=(short)f2bf(f2.w);
        a1[4]=(short)f2bf(f3.x); a1[5]=(short)f2bf(f3.y); a1[6]=(short)f2bf(f3.z); a1[7]=(short)f2bf(f3.w);

        // ---- QK^T: 20 n-tiles, all independent ----
        floatx4 acc[20];
        #pragma unroll
        for (int nt = 0; nt < 20; ++nt) {
            int col = nt * 16 + l15;
            short8 b0 = *(const short8*)&Klds[col][quad * 8];
            short8 b1 = *(const short8*)&Klds[col][32 + quad * 8];
            floatx4 c = {0.f, 0.f, 0.f, 0.f};
            c = __builtin_amdgcn_mfma_f32_16x16x32_bf16(a0, b0, c, 0, 0, 0);
            c = __builtin_amdgcn_mfma_f32_16x16x32_bf16(a1, b1, c, 0, 0, 0);
            acc[nt] = c;
        }

        // ---- per-row/region coefficients (mask bit * scale, or -1 = masked) ----
        float coef[4][4];
        #pragma unroll
        for (int r = 0; r < 4; ++r) {
            int qrow = q0 + quad * 4 + r;
            int mi = (qrow >> 7) * 32 + ((qrow & 63) >> 1);   // nearest-exact 64->32
            #pragma unroll
            for (int rg = 0; rg < 4; ++rg) {
                float mv = dd[rg * 1024 + mi];
                coef[r][rg] = (mv > 0.5f) ? 0.125f * rsv[rg] : -1.0f;
            }
        }

        // ---- mask + scale + row-max (in C-layout registers) ----
        float mx[4] = {-INFINITY, -INFINITY, -INFINITY, -INFINITY};
        #pragma unroll
        for (int nt = 0; nt < 20; ++nt) {
            #pragma unroll
            for (int r = 0; r < 4; ++r) {
                float c;
                if      (nt <  4) c = coef[r][0];
                else if (nt == 4) c = (l15 < 13) ? coef[r][0] : coef[r][1];
                else if (nt <  9) c = coef[r][1];
                else if (nt == 9) c = (l15 < 10) ? coef[r][1] : coef[r][2];
                else if (nt < 14) c = coef[r][2];
                else if (nt ==14) c = (l15 <  7) ? coef[r][2] : coef[r][3];
                else if (nt < 19) c = coef[r][3];
                else              c = (l15 <  4) ? coef[r][3] : -1.0f;
                float sv = (c > 0.f) ? acc[nt][r] * c : -INFINITY;
                acc[nt][r] = sv;
                mx[r] = fmaxf(mx[r], sv);
            }
        }
        #pragma unroll
        for (int off = 1; off < 16; off <<= 1) {
            #pragma unroll
            for (int r = 0; r < 4; ++r) mx[r] = fmaxf(mx[r], __shfl_xor(mx[r], off));
        }

        // ---- exp + row-sum ----
        float sm[4] = {0.f, 0.f, 0.f, 0.f};
        #pragma unroll
        for (int nt = 0; nt < 20; ++nt) {
            #pragma unroll
            for (int r = 0; r < 4; ++r) {
                float p = __expf(acc[nt][r] - mx[r]);   // exp(-inf)=0 for masked
                acc[nt][r] = p;
                sm[r] += p;
            }
        }
        #pragma unroll
        for (int off = 1; off < 16; off <<= 1) {
            #pragma unroll
            for (int r = 0; r < 4; ++r) sm[r] += __shfl_xor(sm[r], off);
        }
        float inv[4];
        #pragma unroll
        for (int r = 0; r < 4; ++r) inv[r] = 1.0f / sm[r];

        // ---- PV: 5 chunks of 64 cols; P transposed via per-wave LDS scratch ----
        floatx4 oacc[4] = {{0.f,0.f,0.f,0.f},{0.f,0.f,0.f,0.f},{0.f,0.f,0.f,0.f},{0.f,0.f,0.f,0.f}};
        #pragma unroll
        for (int c5 = 0; c5 < 5; ++c5) {
            const int buf = c5 & 1;
            #pragma unroll
            for (int nt2 = 0; nt2 < 4; ++nt2) {
                int nt = c5 * 4 + nt2;
                #pragma unroll
                for (int r = 0; r < 4; ++r)
                    Pw[wave][buf][quad * 4 + r][nt2 * 16 + l15] = f2bf(acc[nt][r]);
            }
            #pragma unroll
            for (int ks = 0; ks < 2; ++ks) {
                short8 pa = *(const short8*)&Pw[wave][buf][l15][ks * 32 + quad * 8];
                #pragma unroll
                for (int n = 0; n < 4; ++n) {
                    short8 bv = *(const short8*)&Vt[n * 16 + l15][c5 * 64 + ks * 32 + quad * 8];
                    oacc[n] = __builtin_amdgcn_mfma_f32_16x16x32_bf16(pa, bv, oacc[n], 0, 0, 0);
                }
            }
        }

        // ---- normalize + store (C-layout, direct) ----
        #pragma unroll
        for (int n = 0; n < 4; ++n) {
            #pragma unroll
            for (int r = 0; r < 4; ++r) {
                op[(size_t)(q0 + quad * 4 + r) * INNER + n * 16 + l15] = oacc[n][r] * inv[r];
            }
        }
    }
}

extern "C" void kernel_launch(void* const* d_in, const int* in_sizes, int n_in,
                              void* d_out, int out_size, void* d_ws, size_t ws_size,
                              hipStream_t stream) {
    const float* q  = (const float*)d_in[0];
    const float* k  = (const float*)d_in[1];
    const float* v  = (const float*)d_in[2];
    const float* dd = (const float*)d_in[3];
    float* out = (float*)d_out;
    dd_attn_kernel<<<dim3(256), dim3(512), 0, stream>>>(q, k, v, dd, out);
}

// Round 6
// 105.117 us; speedup vs baseline: 1.0348x; 1.0243x over previous
//
#include <hip/hip_runtime.h>
#include <hip/hip_bf16.h>

typedef __attribute__((ext_vector_type(8))) short short8;
typedef __attribute__((ext_vector_type(4))) float floatx4;

#define HW_TOK 4096
#define KLEN 308
#define DH 64
#define INNER 512

// LDS: one flat ushort pool, XOR-swizzled 16B chunks, ZERO padding.
// K: rows 0..307 (kcol) x 64 ushort.  addrK(row, c[0..7]) = row*64 + ((c^(row&7))<<3)
// V: VBASE + row(dh) * 320.           addrV(row, c[0..39]) = VBASE + row*320 + ((c&~7)|((c^row)&7))<<3
// K tile-19 rows 308..319 read into V region: garbage, masked via kc>=308 -> -inf.
#define VBASE (KLEN * 64)                 // 19712 ushorts
#define LDS_TOTAL (VBASE + DH * 320)      // 40192 ushorts = 80384 B -> 2 blocks/CU

// round-to-nearest-even f32 -> bf16
__device__ __forceinline__ unsigned short f2bf(float f) {
    union { float f; unsigned u; } x; x.f = f;
    unsigned u = x.u;
    return (unsigned short)((u + 0x7FFFu + ((u >> 16) & 1u)) >> 16);
}
__device__ __forceinline__ unsigned pk2bf(float a, float b) {
    return ((unsigned)f2bf(b) << 16) | (unsigned)f2bf(a);
}

// (512,2): measured on this toolchain (R4) to cap VGPR at 128 -> allows 2 blocks/CU.
__global__ __launch_bounds__(512, 2)
void dd_attn_kernel(const float* __restrict__ q,
                    const float* __restrict__ k,
                    const float* __restrict__ v,
                    const float* __restrict__ dd,
                    float* __restrict__ out) {
    __shared__ unsigned short KV[LDS_TOTAL];

    const int tid  = threadIdx.x;
    const int lane = tid & 63;
    const int wave = tid >> 6;
    const int quad = lane >> 4;
    const int l15  = lane & 15;
    const int kxor = l15 & 7;

    const int bid = blockIdx.x;    // 512 blocks
    const int bh  = bid >> 5;      // 0..15
    const int grp = bid & 31;      // 32 groups x 8 waves = 256 q-tiles per (b,h)
    const int b = bh >> 3, h = bh & 7;

    const float* qp = q + (size_t)b * HW_TOK * INNER + h * DH;
    const float* kp = k + (size_t)b * KLEN * INNER + h * DH;
    const float* vp = v + (size_t)b * KLEN * INNER + h * DH;
    float* op = out + (size_t)b * HW_TOK * INNER + h * DH;

    // ---- stage K bf16, swizzled ----
    for (int e = tid; e < KLEN * 32; e += 512) {
        int row = e >> 5, d2 = e & 31;
        float2 f = *(const float2*)(kp + (size_t)row * INNER + 2 * d2);
        int c = d2 >> 2;
        int off = row * 64 + (((c ^ (row & 7)) << 3) | ((d2 & 3) << 1));
        *(unsigned*)&KV[off] = pk2bf(f.x, f.y);
    }
    // ---- stage V^T bf16, swizzled ----
    for (int e = tid; e < KLEN * 32; e += 512) {
        int col = e >> 5, d2 = e & 31;
        float2 f = *(const float2*)(vp + (size_t)col * INNER + 2 * d2);
        int c = col >> 3, c7 = col & 7;
        int r0 = 2 * d2, r1 = r0 + 1;
        KV[VBASE + r0 * 320 + (((c & ~7) | ((c ^ r0) & 7)) << 3) + c7] = f2bf(f.x);
        KV[VBASE + r1 * 320 + (((c & ~7) | ((c ^ r1) & 7)) << 3) + c7] = f2bf(f.y);
    }
    // zero V pad cols 308..319 (avoid NaN/Inf garbage in PV tail)
    for (int e = tid; e < DH * 12; e += 512) {
        int row = e / 12, col = 308 + e % 12;
        int c = col >> 3, c7 = col & 7;
        KV[VBASE + row * 320 + (((c & ~7) | ((c ^ row) & 7)) << 3) + c7] = 0;
    }

    // ---- region sums in registers: quad r sums dd region r, then shfl-broadcast ----
    float rsum = 0.f;
    {
        const float* dp = dd + quad * 1024 + l15 * 4;
        #pragma unroll
        for (int j = 0; j < 16; ++j) {
            float4 f = *(const float4*)(dp + j * 64);
            rsum += f.x + f.y + f.z + f.w;
        }
        #pragma unroll
        for (int off = 1; off < 16; off <<= 1) rsum += __shfl_xor(rsum, off);
    }
    float rsc[4];
    #pragma unroll
    for (int r = 0; r < 4; ++r)
        rsc[r] = 4096.0f / (4.0f * __shfl(rsum, r * 16 + l15));

    __syncthreads();   // the only barrier

    const int q0 = (grp * 8 + wave) * 16;
    const int qrow = q0 + l15;

    // ---- Q B-fragments straight from global (lane n=l15 -> its q row) ----
    const float* qr = qp + (size_t)qrow * INNER + quad * 8;
    float4 f0 = *(const float4*)(qr);
    float4 f1 = *(const float4*)(qr + 4);
    float4 f2 = *(const float4*)(qr + 32);
    float4 f3 = *(const float4*)(qr + 36);
    short8 qa0, qa1;
    qa0[0]=(short)f2bf(f0.x); qa0[1]=(short)f2bf(f0.y); qa0[2]=(short)f2bf(f0.z); qa0[3]=(short)f2bf(f0.w);
    qa0[4]=(short)f2bf(f1.x); qa0[5]=(short)f2bf(f1.y); qa0[6]=(short)f2bf(f1.z); qa0[7]=(short)f2bf(f1.w);
    qa1[0]=(short)f2bf(f2.x); qa1[1]=(short)f2bf(f2.y); qa1[2]=(short)f2bf(f2.z); qa1[3]=(short)f2bf(f2.w);
    qa1[4]=(short)f2bf(f3.x); qa1[5]=(short)f2bf(f3.y); qa1[6]=(short)f2bf(f3.z); qa1[7]=(short)f2bf(f3.w);

    // ---- per-lane mask coefficients (one qrow per lane) ----
    const int mi = (qrow >> 7) * 32 + ((qrow & 63) >> 1);   // nearest-exact 64->32
    float coef[4];
    #pragma unroll
    for (int r = 0; r < 4; ++r)
        coef[r] = (dd[r * 1024 + mi] > 0.5f) ? 0.125f * rsc[r] : -1.0f;

    // ---- flash over 2 chunks of 160 kcols ----
    float m_run = -INFINITY, l_run = 0.f;
    floatx4 oacc[4] = {{0,0,0,0},{0,0,0,0},{0,0,0,0},{0,0,0,0}};

    #pragma unroll
    for (int ch = 0; ch < 2; ++ch) {
        // S^T = K·Q^T : A = K-frag (m=kcol), B = Q-frag (n=qrow)
        floatx4 acc[10];
        #pragma unroll
        for (int t = 0; t < 10; ++t) {
            int row = (ch * 10 + t) * 16 + l15;
            short8 ka0 = *(const short8*)&KV[row * 64 + ((quad       ^ kxor) << 3)];
            short8 ka1 = *(const short8*)&KV[row * 64 + (((4 + quad) ^ kxor) << 3)];
            floatx4 c = {0.f, 0.f, 0.f, 0.f};
            c = __builtin_amdgcn_mfma_f32_16x16x32_bf16(ka0, qa0, c, 0, 0, 0);
            c = __builtin_amdgcn_mfma_f32_16x16x32_bf16(ka1, qa1, c, 0, 0, 0);
            acc[t] = c;
        }

        // mask + scale + lane-local max (kcol = tile*16 + quad*4 + r)
        float mloc = -INFINITY;
        #pragma unroll
        for (int t = 0; t < 10; ++t) {
            #pragma unroll
            for (int r = 0; r < 4; ++r) {
                int kc = (ch * 10 + t) * 16 + quad * 4 + r;
                float cf = (kc < 77) ? coef[0] : (kc < 154) ? coef[1]
                         : (kc < 231) ? coef[2] : (kc < 308) ? coef[3] : -1.0f;
                float sv = (cf > 0.f) ? acc[t][r] * cf : -INFINITY;
                acc[t][r] = sv;
                mloc = fmaxf(mloc, sv);
            }
        }
        mloc = fmaxf(mloc, __shfl_xor(mloc, 16));
        mloc = fmaxf(mloc, __shfl_xor(mloc, 32));

        float m_new = fmaxf(m_run, mloc);      // chunk0: mloc finite (region 0 always on)
        float alpha = __expf(m_run - m_new);   // chunk0: exp(-inf)=0
        float lloc = 0.f;
        #pragma unroll
        for (int t = 0; t < 10; ++t) {
            #pragma unroll
            for (int r = 0; r < 4; ++r) {
                float p = __expf(acc[t][r] - m_new);
                acc[t][r] = p;
                lloc += p;
            }
        }
        lloc += __shfl_xor(lloc, 16);
        lloc += __shfl_xor(lloc, 32);
        l_run = l_run * alpha + lloc;
        m_run = m_new;
        #pragma unroll
        for (int n = 0; n < 4; ++n)
            #pragma unroll
            for (int r = 0; r < 4; ++r) oacc[n][r] *= alpha;

        // PV: out^T += V^T · P^T.  Build P^T B-frag via 4-lane permutation (same l15).
        const int sl0 = ((quad & 1) << 5) + l15;   // src lane for j0..3
        const int sl1 = sl0 + 16;                  // src lane for j4..7
        const bool hi = (quad >= 2);               // tile select within 32-k chunk
        #pragma unroll
        for (int c32 = 0; c32 < 5; ++c32) {
            floatx4 pA = acc[2 * c32];
            floatx4 pB = acc[2 * c32 + 1];
            unsigned uA0 = pk2bf(pA[0], pA[1]), uA1 = pk2bf(pA[2], pA[3]);
            unsigned uB0 = pk2bf(pB[0], pB[1]), uB1 = pk2bf(pB[2], pB[3]);
            unsigned xA0 = (unsigned)__shfl((int)uA0, sl0), xB0 = (unsigned)__shfl((int)uB0, sl0);
            unsigned xA1 = (unsigned)__shfl((int)uA1, sl0), xB1 = (unsigned)__shfl((int)uB1, sl0);
            unsigned yA0 = (unsigned)__shfl((int)uA0, sl1), yB0 = (unsigned)__shfl((int)uB0, sl1);
            unsigned yA1 = (unsigned)__shfl((int)uA1, sl1), yB1 = (unsigned)__shfl((int)uB1, sl1);
            union { short8 s; unsigned u[4]; } pu;
            pu.u[0] = hi ? xB0 : xA0;   // j0,j1
            pu.u[1] = hi ? xB1 : xA1;   // j2,j3
            pu.u[2] = hi ? yB0 : yA0;   // j4,j5
            pu.u[3] = hi ? yB1 : yA1;   // j6,j7
            #pragma unroll
            for (int n = 0; n < 4; ++n) {
                int row = n * 16 + l15;
                int c = ch * 20 + c32 * 4 + quad;
                int cs = (c & ~7) | ((c ^ kxor) & 7);
                short8 va = *(const short8*)&KV[VBASE + row * 320 + (cs << 3)];
                oacc[n] = __builtin_amdgcn_mfma_f32_16x16x32_bf16(va, pu.s, oacc[n], 0, 0, 0);
            }
        }
    }

    // ---- normalize + store out^T C-layout: lane l15 = qrow, dh = n*16 + quad*4 + r ----
    const float inv = 1.0f / l_run;
    #pragma unroll
    for (int n = 0; n < 4; ++n) {
        float4 o;
        o.x = oacc[n][0] * inv;
        o.y = oacc[n][1] * inv;
        o.z = oacc[n][2] * inv;
        o.w = oacc[n][3] * inv;
        *(float4*)&op[(size_t)qrow * INNER + n * 16 + quad * 4] = o;
    }
}

extern "C" void kernel_launch(void* const* d_in, const int* in_sizes, int n_in,
                              void* d_out, int out_size, void* d_ws, size_t ws_size,
                              hipStream_t stream) {
    const float* q  = (const float*)d_in[0];
    const float* k  = (const float*)d_in[1];
    const float* v  = (const float*)d_in[2];
    const float* dd = (const float*)d_in[3];
    float* out = (float*)d_out;
    dd_attn_kernel<<<dim3(512), dim3(512), 0, stream>>>(q, k, v, dd, out);
}

// Round 7
// 93.594 us; speedup vs baseline: 1.1622x; 1.1231x over previous
//
#include <hip/hip_runtime.h>
#include <hip/hip_bf16.h>

typedef __attribute__((ext_vector_type(8))) short short8;
typedef __attribute__((ext_vector_type(4))) float floatx4;

#define HW_TOK 4096
#define KLEN 308
#define DH 64
#define INNER 512

#define KROWS 320                      // K LDS rows incl. pad (rows 308..319 garbage, masked)
#define VSTRU 328                      // V^T row stride in ushorts (16B multiple)
#define VBASE (KROWS * 64)             // 20480 ushorts
#define KV_TOTAL (VBASE + DH * VSTRU)  // 41472 u = 82944 B
#define PSTR 40                        // P bounce row stride in ushorts (80 B = 16B mult)

// round-to-nearest-even f32 -> bf16
__device__ __forceinline__ unsigned short f2bf(float f) {
    union { float f; unsigned u; } x; x.f = f;
    unsigned u = x.u;
    return (unsigned short)((u + 0x7FFFu + ((u >> 16) & 1u)) >> 16);
}
__device__ __forceinline__ unsigned pk2bf(float a, float b) {
    return ((unsigned)f2bf(b) << 16) | (unsigned)f2bf(a);
}

__global__ __launch_bounds__(512, 1)   // 1 block/CU (LDS-bound anyway) -> 256 VGPR cap
void dd_attn_kernel(const float* __restrict__ q,
                    const float* __restrict__ k,
                    const float* __restrict__ v,
                    const float* __restrict__ dd,
                    float* __restrict__ out) {
    __shared__ unsigned short KV[KV_TOTAL];
    __shared__ unsigned short Pb[8][2][16][PSTR];   // [wave][qt][qrow][32 kcols + pad]

    const int tid  = threadIdx.x;
    const int lane = tid & 63;
    const int wave = tid >> 6;
    const int quad = lane >> 4;
    const int l15  = lane & 15;

    const int bid = blockIdx.x;    // 256 blocks
    const int bh  = bid >> 4;      // 0..15
    const int grp = bid & 15;      // 16 groups x 8 waves x 32 rows = 4096
    const int b = bh >> 3, h = bh & 7;

    const float* qp = q + (size_t)b * HW_TOK * INNER + h * DH;
    const float* kp = k + (size_t)b * KLEN * INNER + h * DH;
    const float* vp = v + (size_t)b * KLEN * INNER + h * DH;
    float* op = out + (size_t)b * HW_TOK * INNER + h * DH;

    // ---- stage K bf16, swizzled 16B chunks (conflict-free b32 writes) ----
    for (int e = tid; e < KLEN * 32; e += 512) {
        int row = e >> 5, d2 = e & 31;
        float2 f = *(const float2*)(kp + (size_t)row * INNER + 2 * d2);
        int c = d2 >> 2;
        int off = row * 64 + (((c ^ (row & 7)) << 3) | ((d2 & 3) << 1));
        *(unsigned*)&KV[off] = pk2bf(f.x, f.y);
    }
    // ---- stage V^T bf16: lane=dh, coalesced row reads, one b128 write per 8 cols ----
    #pragma unroll
    for (int i = 0; i < 5; ++i) {
        int cq = wave + 8 * i;                    // 8 waves x 5 = 40 col-chunks
        float f[8];
        #pragma unroll
        for (int j = 0; j < 8; ++j) {
            int col = cq * 8 + j;
            f[j] = (col < KLEN) ? vp[(size_t)col * INNER + lane] : 0.f;  // wave-uniform branch
        }
        union { short8 s; unsigned u[4]; } vv;
        #pragma unroll
        for (int j = 0; j < 4; ++j) vv.u[j] = pk2bf(f[2 * j], f[2 * j + 1]);
        int swz = (cq & ~7) | ((cq ^ (lane & 7)) & 7);
        *(short8*)&KV[VBASE + lane * VSTRU + (swz << 3)] = vv.s;
    }
    // ---- region sums: quad r sums dd region r, shfl-broadcast ----
    float rsum = 0.f;
    {
        const float* dp = dd + quad * 1024 + l15 * 4;
        #pragma unroll
        for (int j = 0; j < 16; ++j) {
            float4 f = *(const float4*)(dp + j * 64);
            rsum += f.x + f.y + f.z + f.w;
        }
        #pragma unroll
        for (int off = 1; off < 16; off <<= 1) rsum += __shfl_xor(rsum, off);
    }
    float rsc[4];
    #pragma unroll
    for (int r = 0; r < 4; ++r)
        rsc[r] = 4096.0f / (4.0f * __shfl(rsum, r * 16 + l15));

    __syncthreads();   // the only barrier

    const int q0 = (grp * 8 + wave) * 32;

    // ---- Q B-fragments for 2 q-tiles, straight from global ----
    short8 qa[2][2];
    #pragma unroll
    for (int qt = 0; qt < 2; ++qt) {
        const float* qr = qp + (size_t)(q0 + qt * 16 + l15) * INNER + quad * 8;
        float4 g0 = *(const float4*)(qr);
        float4 g1 = *(const float4*)(qr + 4);
        float4 g2 = *(const float4*)(qr + 32);
        float4 g3 = *(const float4*)(qr + 36);
        union { short8 s; unsigned u[4]; } ua, ub;
        ua.u[0] = pk2bf(g0.x, g0.y); ua.u[1] = pk2bf(g0.z, g0.w);
        ua.u[2] = pk2bf(g1.x, g1.y); ua.u[3] = pk2bf(g1.z, g1.w);
        ub.u[0] = pk2bf(g2.x, g2.y); ub.u[1] = pk2bf(g2.z, g2.w);
        ub.u[2] = pk2bf(g3.x, g3.y); ub.u[3] = pk2bf(g3.z, g3.w);
        qa[qt][0] = ua.s; qa[qt][1] = ub.s;
    }
    // ---- per-lane mask coefficients (lane l15 = qrow within tile) ----
    float coef[2][4];
    #pragma unroll
    for (int qt = 0; qt < 2; ++qt) {
        int qrow = q0 + qt * 16 + l15;
        int mi = (qrow >> 7) * 32 + ((qrow & 63) >> 1);   // nearest-exact 64->32
        #pragma unroll
        for (int r = 0; r < 4; ++r)
            coef[qt][r] = (dd[r * 1024 + mi] > 0.5f) ? 0.125f * rsc[r] : -1.0f;
    }

    // ---- flash over 4 chunks: 96,96,96,32 kcols ----
    float m_run[2] = {-INFINITY, -INFINITY};
    float l_run[2] = {0.f, 0.f};
    floatx4 oacc[2][4] = {{{0,0,0,0},{0,0,0,0},{0,0,0,0},{0,0,0,0}},
                          {{0,0,0,0},{0,0,0,0},{0,0,0,0},{0,0,0,0}}};

    #pragma unroll
    for (int ch = 0; ch < 4; ++ch) {
        const int NT = (ch < 3) ? 6 : 2;        // S^T tiles this chunk
        floatx4 acc[2][6];

        // S^T = K·Q^T : K-frags shared across both q-tiles
        #pragma unroll
        for (int t = 0; t < NT; ++t) {
            int row = (ch * 6 + t) * 16 + l15;
            short8 ka0 = *(const short8*)&KV[row * 64 + (((quad    ) ^ (row & 7)) << 3)];
            short8 ka1 = *(const short8*)&KV[row * 64 + (((4 + quad) ^ (row & 7)) << 3)];
            #pragma unroll
            for (int qt = 0; qt < 2; ++qt) {
                floatx4 c = {0.f, 0.f, 0.f, 0.f};
                c = __builtin_amdgcn_mfma_f32_16x16x32_bf16(ka0, qa[qt][0], c, 0, 0, 0);
                c = __builtin_amdgcn_mfma_f32_16x16x32_bf16(ka1, qa[qt][1], c, 0, 0, 0);
                acc[qt][t] = c;
            }
        }

        // mask + scale + online softmax (per q-tile, reductions over quad only)
        #pragma unroll
        for (int qt = 0; qt < 2; ++qt) {
            float mloc = -INFINITY;
            #pragma unroll
            for (int t = 0; t < NT; ++t) {
                #pragma unroll
                for (int r = 0; r < 4; ++r) {
                    int kc = (ch * 6 + t) * 16 + quad * 4 + r;
                    float cf = (kc < 77) ? coef[qt][0] : (kc < 154) ? coef[qt][1]
                             : (kc < 231) ? coef[qt][2] : (kc < 308) ? coef[qt][3] : -1.0f;
                    float sv = (cf > 0.f) ? acc[qt][t][r] * cf : -INFINITY;
                    acc[qt][t][r] = sv;
                    mloc = fmaxf(mloc, sv);
                }
            }
            mloc = fmaxf(mloc, __shfl_xor(mloc, 16));
            mloc = fmaxf(mloc, __shfl_xor(mloc, 32));
            float m_new = fmaxf(m_run[qt], mloc);   // finite from chunk 0 on (region 0 open)
            float alpha = __expf(m_run[qt] - m_new);
            float lloc = 0.f;
            #pragma unroll
            for (int t = 0; t < NT; ++t) {
                #pragma unroll
                for (int r = 0; r < 4; ++r) {
                    float p = __expf(acc[qt][t][r] - m_new);
                    acc[qt][t][r] = p;
                    lloc += p;
                }
            }
            lloc += __shfl_xor(lloc, 16);
            lloc += __shfl_xor(lloc, 32);
            l_run[qt] = l_run[qt] * alpha + lloc;
            m_run[qt] = m_new;
            #pragma unroll
            for (int n = 0; n < 4; ++n)
                #pragma unroll
                for (int r = 0; r < 4; ++r) oacc[qt][n][r] *= alpha;
        }

        // PV: out^T += V^T · P^T ; P transposed via per-wave LDS bounce
        const int NS = NT / 2;
        #pragma unroll
        for (int s = 0; s < NS; ++s) {
            #pragma unroll
            for (int qt = 0; qt < 2; ++qt) {
                unsigned p0 = pk2bf(acc[qt][2*s][0],     acc[qt][2*s][1]);
                unsigned p1 = pk2bf(acc[qt][2*s][2],     acc[qt][2*s][3]);
                unsigned p2 = pk2bf(acc[qt][2*s+1][0],   acc[qt][2*s+1][1]);
                unsigned p3 = pk2bf(acc[qt][2*s+1][2],   acc[qt][2*s+1][3]);
                *(uint2*)&Pb[wave][qt][l15][quad * 4]      = make_uint2(p0, p1);
                *(uint2*)&Pb[wave][qt][l15][16 + quad * 4] = make_uint2(p2, p3);
            }
            short8 pbv[2];
            #pragma unroll
            for (int qt = 0; qt < 2; ++qt)
                pbv[qt] = *(const short8*)&Pb[wave][qt][l15][quad * 8];
            #pragma unroll
            for (int n = 0; n < 4; ++n) {
                int row = n * 16 + l15;
                int cq = ch * 12 + s * 4 + quad;
                int swz = (cq & ~7) | ((cq ^ (row & 7)) & 7);
                short8 va = *(const short8*)&KV[VBASE + row * VSTRU + (swz << 3)];
                #pragma unroll
                for (int qt = 0; qt < 2; ++qt)
                    oacc[qt][n] = __builtin_amdgcn_mfma_f32_16x16x32_bf16(va, pbv[qt], oacc[qt][n], 0, 0, 0);
            }
        }
    }

    // ---- normalize + store out^T C-layout (float4 per n-tile) ----
    #pragma unroll
    for (int qt = 0; qt < 2; ++qt) {
        float inv = 1.0f / l_run[qt];
        float* o = op + (size_t)(q0 + qt * 16 + l15) * INNER + quad * 4;
        #pragma unroll
        for (int n = 0; n < 4; ++n) {
            float4 ov;
            ov.x = oacc[qt][n][0] * inv;
            ov.y = oacc[qt][n][1] * inv;
            ov.z = oacc[qt][n][2] * inv;
            ov.w = oacc[qt][n][3] * inv;
            *(float4*)&o[n * 16] = ov;
        }
    }
}

extern "C" void kernel_launch(void* const* d_in, const int* in_sizes, int n_in,
                              void* d_out, int out_size, void* d_ws, size_t ws_size,
                              hipStream_t stream) {
    const float* q  = (const float*)d_in[0];
    const float* k  = (const float*)d_in[1];
    const float* v  = (const float*)d_in[2];
    const float* dd = (const float*)d_in[3];
    float* out = (float*)d_out;
    dd_attn_kernel<<<dim3(256), dim3(512), 0, stream>>>(q, k, v, dd, out);
}

// Round 8
// 93.193 us; speedup vs baseline: 1.1672x; 1.0043x over previous
//
#include <hip/hip_runtime.h>
#include <hip/hip_bf16.h>

typedef __attribute__((ext_vector_type(8))) short short8;
typedef __attribute__((ext_vector_type(4))) float floatx4;

#define HW_TOK 4096
#define KLEN 308
#define DH 64
#define INNER 512

#define KROWS 320                      // K LDS rows incl. zeroed pad rows 308..319
#define VSTRU 328                      // V^T row stride in ushorts (16B multiple)
#define VBASE (KROWS * 64)             // 20480 ushorts
#define KV_TOTAL (VBASE + DH * VSTRU)  // 41472 u = 82944 B
#define PSTR 40                        // P bounce row stride in ushorts
#define NWAVES 16

// round-to-nearest-even f32 -> bf16
__device__ __forceinline__ unsigned short f2bf(float f) {
    union { float f; unsigned u; } x; x.f = f;
    unsigned u = x.u;
    return (unsigned short)((u + 0x7FFFu + ((u >> 16) & 1u)) >> 16);
}
__device__ __forceinline__ unsigned pk2bf(float a, float b) {
    return ((unsigned)f2bf(b) << 16) | (unsigned)f2bf(a);
}

// 1024-thread block = 16 waves/CU (4/SIMD) at ~103 KB LDS -> 2x latency hiding vs R7.
// VGPR cap at 4 waves/SIMD = 128; 1-qtile live set ~80 (R6-measured) -> no spills.
__global__ __launch_bounds__(1024, 1)
void dd_attn_kernel(const float* __restrict__ q,
                    const float* __restrict__ k,
                    const float* __restrict__ v,
                    const float* __restrict__ dd,
                    float* __restrict__ out) {
    __shared__ unsigned short KV[KV_TOTAL];
    __shared__ unsigned short Pb[NWAVES][16][PSTR];   // 20480 B, per-wave bounce

    const int tid  = threadIdx.x;
    const int lane = tid & 63;
    const int wave = tid >> 6;     // 0..15
    const int quad = lane >> 4;
    const int l15  = lane & 15;

    const int bid = blockIdx.x;    // 256 blocks
    const int bh  = bid >> 4;      // 0..15
    const int grp = bid & 15;      // 16 groups x 16 waves x 16 rows = 4096
    const int b = bh >> 3, h = bh & 7;

    const float* qp = q + (size_t)b * HW_TOK * INNER + h * DH;
    const float* kp = k + (size_t)b * KLEN * INNER + h * DH;
    const float* vp = v + (size_t)b * KLEN * INNER + h * DH;
    float* op = out + (size_t)b * HW_TOK * INNER + h * DH;

    // ---- stage K bf16, swizzled 16B chunks ----
    for (int e = tid; e < KLEN * 32; e += 1024) {
        int row = e >> 5, d2 = e & 31;
        float2 f = *(const float2*)(kp + (size_t)row * INNER + 2 * d2);
        int c = d2 >> 2;
        int off = row * 64 + (((c ^ (row & 7)) << 3) | ((d2 & 3) << 1));
        *(unsigned*)&KV[off] = pk2bf(f.x, f.y);
    }
    // zero K pad rows 308..319 (read by tile 19, masked, but keep NaN-free)
    for (int e = tid; e < 12 * 64; e += 1024) KV[KLEN * 64 + e] = 0;

    // ---- stage V^T bf16: lane=dh, coalesced row reads, one b128 write per 8 cols ----
    #pragma unroll
    for (int i = 0; i < 3; ++i) {
        int cq = wave + NWAVES * i;               // 16 waves x 3 = 48 -> use cq<40
        if (cq < 40) {                            // wave-uniform branch
            float f[8];
            #pragma unroll
            for (int j = 0; j < 8; ++j) {
                int col = cq * 8 + j;
                f[j] = (col < KLEN) ? vp[(size_t)col * INNER + lane] : 0.f;
            }
            union { short8 s; unsigned u[4]; } vv;
            #pragma unroll
            for (int j = 0; j < 4; ++j) vv.u[j] = pk2bf(f[2 * j], f[2 * j + 1]);
            int swz = (cq & ~7) | ((cq ^ (lane & 7)) & 7);
            *(short8*)&KV[VBASE + lane * VSTRU + (swz << 3)] = vv.s;
        }
    }
    // ---- region sums: quad r sums dd region r, shfl-broadcast ----
    float rsum = 0.f;
    {
        const float* dp = dd + quad * 1024 + l15 * 4;
        #pragma unroll
        for (int j = 0; j < 16; ++j) {
            float4 f = *(const float4*)(dp + j * 64);
            rsum += f.x + f.y + f.z + f.w;
        }
        #pragma unroll
        for (int off = 1; off < 16; off <<= 1) rsum += __shfl_xor(rsum, off);
    }
    float rsc[4];
    #pragma unroll
    for (int r = 0; r < 4; ++r)
        rsc[r] = 4096.0f / (4.0f * __shfl(rsum, r * 16 + l15));

    __syncthreads();   // the only barrier

    const int q0 = (grp * NWAVES + wave) * 16;
    const int qrow = q0 + l15;

    // ---- Q B-fragment straight from global (lane n=l15 -> its q row) ----
    const float* qr = qp + (size_t)qrow * INNER + quad * 8;
    float4 g0 = *(const float4*)(qr);
    float4 g1 = *(const float4*)(qr + 4);
    float4 g2 = *(const float4*)(qr + 32);
    float4 g3 = *(const float4*)(qr + 36);
    short8 qa0, qa1;
    {
        union { short8 s; unsigned u[4]; } ua, ub;
        ua.u[0] = pk2bf(g0.x, g0.y); ua.u[1] = pk2bf(g0.z, g0.w);
        ua.u[2] = pk2bf(g1.x, g1.y); ua.u[3] = pk2bf(g1.z, g1.w);
        ub.u[0] = pk2bf(g2.x, g2.y); ub.u[1] = pk2bf(g2.z, g2.w);
        ub.u[2] = pk2bf(g3.x, g3.y); ub.u[3] = pk2bf(g3.z, g3.w);
        qa0 = ua.s; qa1 = ub.s;
    }

    // ---- per-lane mask coefficients ----
    const int mi = (qrow >> 7) * 32 + ((qrow & 63) >> 1);   // nearest-exact 64->32
    float coef[4];
    #pragma unroll
    for (int r = 0; r < 4; ++r)
        coef[r] = (dd[r * 1024 + mi] > 0.5f) ? 0.125f * rsc[r] : -1.0f;

    // ---- flash over 4 chunks: 96,96,96,32 kcols ----
    float m_run = -INFINITY, l_run = 0.f;
    floatx4 oacc[4] = {{0,0,0,0},{0,0,0,0},{0,0,0,0},{0,0,0,0}};

    #pragma unroll
    for (int ch = 0; ch < 4; ++ch) {
        const int NT = (ch < 3) ? 6 : 2;
        floatx4 acc[6];

        // S^T = K·Q^T
        #pragma unroll
        for (int t = 0; t < NT; ++t) {
            int row = (ch * 6 + t) * 16 + l15;
            short8 ka0 = *(const short8*)&KV[row * 64 + (((quad    ) ^ (row & 7)) << 3)];
            short8 ka1 = *(const short8*)&KV[row * 64 + (((4 + quad) ^ (row & 7)) << 3)];
            floatx4 c = {0.f, 0.f, 0.f, 0.f};
            c = __builtin_amdgcn_mfma_f32_16x16x32_bf16(ka0, qa0, c, 0, 0, 0);
            c = __builtin_amdgcn_mfma_f32_16x16x32_bf16(ka1, qa1, c, 0, 0, 0);
            acc[t] = c;
        }

        // mask + scale + online softmax (reductions over quad only: off 16,32)
        float mloc = -INFINITY;
        #pragma unroll
        for (int t = 0; t < NT; ++t) {
            #pragma unroll
            for (int r = 0; r < 4; ++r) {
                int kc = (ch * 6 + t) * 16 + quad * 4 + r;
                float cf = (kc < 77) ? coef[0] : (kc < 154) ? coef[1]
                         : (kc < 231) ? coef[2] : (kc < 308) ? coef[3] : -1.0f;
                float sv = (cf > 0.f) ? acc[t][r] * cf : -INFINITY;
                acc[t][r] = sv;
                mloc = fmaxf(mloc, sv);
            }
        }
        mloc = fmaxf(mloc, __shfl_xor(mloc, 16));
        mloc = fmaxf(mloc, __shfl_xor(mloc, 32));
        float m_new = fmaxf(m_run, mloc);   // finite from chunk 0 (region 0 open)
        float alpha = __expf(m_run - m_new);
        float lloc = 0.f;
        #pragma unroll
        for (int t = 0; t < NT; ++t) {
            #pragma unroll
            for (int r = 0; r < 4; ++r) {
                float p = __expf(acc[t][r] - m_new);
                acc[t][r] = p;
                lloc += p;
            }
        }
        lloc += __shfl_xor(lloc, 16);
        lloc += __shfl_xor(lloc, 32);
        l_run = l_run * alpha + lloc;
        m_run = m_new;
        #pragma unroll
        for (int n = 0; n < 4; ++n)
            #pragma unroll
            for (int r = 0; r < 4; ++r) oacc[n][r] *= alpha;

        // PV: out^T += V^T · P^T ; P transposed via per-wave LDS bounce
        const int NS = NT / 2;
        #pragma unroll
        for (int s = 0; s < NS; ++s) {
            unsigned p0 = pk2bf(acc[2*s][0],   acc[2*s][1]);
            unsigned p1 = pk2bf(acc[2*s][2],   acc[2*s][3]);
            unsigned p2 = pk2bf(acc[2*s+1][0], acc[2*s+1][1]);
            unsigned p3 = pk2bf(acc[2*s+1][2], acc[2*s+1][3]);
            // same-wave in-order DS: write-then-read needs no barrier (R2/R7-proven)
            *(uint2*)&Pb[wave][l15][quad * 4]      = make_uint2(p0, p1);
            *(uint2*)&Pb[wave][l15][16 + quad * 4] = make_uint2(p2, p3);
            short8 pbv = *(const short8*)&Pb[wave][l15][quad * 8];
            #pragma unroll
            for (int n = 0; n < 4; ++n) {
                int row = n * 16 + l15;
                int cq = ch * 12 + s * 4 + quad;
                int swz = (cq & ~7) | ((cq ^ (row & 7)) & 7);
                short8 va = *(const short8*)&KV[VBASE + row * VSTRU + (swz << 3)];
                oacc[n] = __builtin_amdgcn_mfma_f32_16x16x32_bf16(va, pbv, oacc[n], 0, 0, 0);
            }
        }
    }

    // ---- normalize + store out^T C-layout (float4 per n-tile) ----
    const float inv = 1.0f / l_run;
    float* o = op + (size_t)qrow * INNER + quad * 4;
    #pragma unroll
    for (int n = 0; n < 4; ++n) {
        float4 ov;
        ov.x = oacc[n][0] * inv;
        ov.y = oacc[n][1] * inv;
        ov.z = oacc[n][2] * inv;
        ov.w = oacc[n][3] * inv;
        *(float4*)&o[n * 16] = ov;
    }
}

extern "C" void kernel_launch(void* const* d_in, const int* in_sizes, int n_in,
                              void* d_out, int out_size, void* d_ws, size_t ws_size,
                              hipStream_t stream) {
    const float* q  = (const float*)d_in[0];
    const float* k  = (const float*)d_in[1];
    const float* v  = (const float*)d_in[2];
    const float* dd = (const float*)d_in[3];
    float* out = (float*)d_out;
    dd_attn_kernel<<<dim3(256), dim3(1024), 0, stream>>>(q, k, v, dd, out);
}

// Round 9
// 91.255 us; speedup vs baseline: 1.1920x; 1.0212x over previous
//
#include <hip/hip_runtime.h>
#include <hip/hip_bf16.h>

typedef __attribute__((ext_vector_type(8))) short short8;
typedef __attribute__((ext_vector_type(16))) float floatx16;

#define HW_TOK 4096
#define KLEN 308
#define DH 64
#define INNER 512

#define KROWS 320                      // K LDS rows incl. zeroed pad rows 308..319
#define VSTRU 328                      // V^T row stride in ushorts (16B multiple)
#define VBASE (KROWS * 64)             // 20480 ushorts
#define KV_TOTAL (VBASE + DH * VSTRU)  // 41472 u = 82944 B
#define PSTRU 40                       // P bounce row stride in ushorts (80 B, 16B-aligned)
#define NW 8

// round-to-nearest-even f32 -> bf16
__device__ __forceinline__ unsigned short f2bf(float f) {
    union { float f; unsigned u; } x; x.f = f;
    unsigned u = x.u;
    return (unsigned short)((u + 0x7FFFu + ((u >> 16) & 1u)) >> 16);
}
__device__ __forceinline__ unsigned pk2bf(float a, float b) {
    return ((unsigned)f2bf(b) << 16) | (unsigned)f2bf(a);
}

__global__ __launch_bounds__(512, 1)   // 1 block/CU -> 2 waves/SIMD -> 256 VGPR cap
void dd_attn_kernel(const float* __restrict__ q,
                    const float* __restrict__ k,
                    const float* __restrict__ v,
                    const float* __restrict__ dd,
                    float* __restrict__ out) {
    __shared__ unsigned short KV[KV_TOTAL];
    __shared__ unsigned short Pb[NW][32][PSTRU];   // 20480 B per-wave P^T bounce

    const int tid  = threadIdx.x;
    const int lane = tid & 63;
    const int wave = tid >> 6;     // 0..7
    const int half = lane >> 5;    // 0..1  (k-half for 32x32x16 A/B frags)
    const int l31  = lane & 31;
    const int quad = lane >> 4;
    const int l15  = lane & 15;

    const int bid = blockIdx.x;    // 256 blocks
    const int bh  = bid >> 4;      // 0..15
    const int grp = bid & 15;      // 16 groups x 8 waves x 32 rows = 4096
    const int b = bh >> 3, h = bh & 7;

    const float* qp = q + (size_t)b * HW_TOK * INNER + h * DH;
    const float* kp = k + (size_t)b * KLEN * INNER + h * DH;
    const float* vp = v + (size_t)b * KLEN * INNER + h * DH;
    float* op = out + (size_t)b * HW_TOK * INNER + h * DH;

    // ---- stage K bf16, swizzled 16B chunks ----
    for (int e = tid; e < KLEN * 32; e += 512) {
        int row = e >> 5, d2 = e & 31;
        float2 f = *(const float2*)(kp + (size_t)row * INNER + 2 * d2);
        int c = d2 >> 2;
        int off = row * 64 + (((c ^ (row & 7)) << 3) | ((d2 & 3) << 1));
        *(unsigned*)&KV[off] = pk2bf(f.x, f.y);
    }
    for (int e = tid; e < 12 * 64; e += 512) KV[KLEN * 64 + e] = 0;   // zero K pad rows

    // ---- stage V^T bf16: lane=dh, coalesced row reads, one b128 write per 8 cols ----
    #pragma unroll
    for (int i = 0; i < 5; ++i) {
        int cq = wave + NW * i;                   // 8 waves x 5 = 40 col-chunks
        float f[8];
        #pragma unroll
        for (int j = 0; j < 8; ++j) {
            int col = cq * 8 + j;
            f[j] = (col < KLEN) ? vp[(size_t)col * INNER + lane] : 0.f;
        }
        union { short8 s; unsigned u[4]; } vv;
        #pragma unroll
        for (int j = 0; j < 4; ++j) vv.u[j] = pk2bf(f[2 * j], f[2 * j + 1]);
        int swz = (cq & ~7) | ((cq ^ (lane & 7)) & 7);
        *(short8*)&KV[VBASE + lane * VSTRU + (swz << 3)] = vv.s;
    }
    // ---- region sums: quad r sums dd region r, shfl-broadcast ----
    float rsum = 0.f;
    {
        const float* dp = dd + quad * 1024 + l15 * 4;
        #pragma unroll
        for (int j = 0; j < 16; ++j) {
            float4 f = *(const float4*)(dp + j * 64);
            rsum += f.x + f.y + f.z + f.w;
        }
        #pragma unroll
        for (int off = 1; off < 16; off <<= 1) rsum += __shfl_xor(rsum, off);
    }
    float rsc[4];
    #pragma unroll
    for (int r = 0; r < 4; ++r)
        rsc[r] = 4096.0f / (4.0f * __shfl(rsum, r * 16 + l15));

    __syncthreads();   // the only barrier

    const int q0 = (grp * NW + wave) * 32;
    const int qrow = q0 + l31;               // this lane's q row (both halves same row)

    // ---- Q B-fragments (32x32x16: n=l31, k=half*8+j per 16-k step) ----
    short8 qb[4];
    const float* qr = qp + (size_t)qrow * INNER;
    #pragma unroll
    for (int ks = 0; ks < 4; ++ks) {
        const float* p0 = qr + ks * 16 + half * 8;
        float4 a = *(const float4*)p0;
        float4 c = *(const float4*)(p0 + 4);
        union { short8 s; unsigned u[4]; } u;
        u.u[0] = pk2bf(a.x, a.y); u.u[1] = pk2bf(a.z, a.w);
        u.u[2] = pk2bf(c.x, c.y); u.u[3] = pk2bf(c.z, c.w);
        qb[ks] = u.s;
    }

    // ---- per-lane mask coefficients ----
    const int mi = (qrow >> 7) * 32 + ((qrow & 63) >> 1);   // nearest-exact 64->32
    float coef[4];
    #pragma unroll
    for (int r = 0; r < 4; ++r)
        coef[r] = (dd[r * 1024 + mi] > 0.5f) ? 0.125f * rsc[r] : -1.0f;

    // ---- flash over 2 chunks of 160 kcols (5 m-tiles of 32 each) ----
    float m_run = -INFINITY, l_run = 0.f;
    floatx16 oacc[2];
    #pragma unroll
    for (int j = 0; j < 16; ++j) { oacc[0][j] = 0.f; oacc[1][j] = 0.f; }

    #pragma unroll
    for (int ch = 0; ch < 2; ++ch) {
        floatx16 acc[5];

        // S^T = K·Q^T : A = K (m=kcol), B = Q (n=qrow)
        #pragma unroll
        for (int t = 0; t < 5; ++t) {
            int row = (ch * 5 + t) * 32 + l31;
            floatx16 c;
            #pragma unroll
            for (int j = 0; j < 16; ++j) c[j] = 0.f;
            #pragma unroll
            for (int ks = 0; ks < 4; ++ks) {
                int cc = ks * 2 + half;
                short8 ka = *(const short8*)&KV[row * 64 + ((cc ^ (row & 7)) << 3)];
                c = __builtin_amdgcn_mfma_f32_32x32x16_bf16(ka, qb[ks], c, 0, 0, 0);
            }
            acc[t] = c;
        }

        // mask + scale + tree-max (C-layout: kcol = 32*tile + (reg&3)+8*(reg>>2)+4*half)
        float mloc = -INFINITY;
        #pragma unroll
        for (int t = 0; t < 5; ++t) {
            #pragma unroll
            for (int reg = 0; reg < 16; ++reg) {
                const int C0 = (ch * 5 + t) * 32 + (reg & 3) + 8 * (reg >> 2);
                const int C1 = C0 + 4;
                float cfA = (C0 < 77) ? coef[0] : (C0 < 154) ? coef[1]
                          : (C0 < 231) ? coef[2] : (C0 < 308) ? coef[3] : -1.0f;
                float cfB = (C1 < 77) ? coef[0] : (C1 < 154) ? coef[1]
                          : (C1 < 231) ? coef[2] : (C1 < 308) ? coef[3] : -1.0f;
                float cf = half ? cfB : cfA;
                float sv = (cf > 0.f) ? acc[t][reg] * cf : -INFINITY;
                acc[t][reg] = sv;
            }
            float m0 = fmaxf(fmaxf(acc[t][0], acc[t][1]),  fmaxf(acc[t][2], acc[t][3]));
            float m1 = fmaxf(fmaxf(acc[t][4], acc[t][5]),  fmaxf(acc[t][6], acc[t][7]));
            float m2 = fmaxf(fmaxf(acc[t][8], acc[t][9]),  fmaxf(acc[t][10], acc[t][11]));
            float m3 = fmaxf(fmaxf(acc[t][12], acc[t][13]), fmaxf(acc[t][14], acc[t][15]));
            mloc = fmaxf(mloc, fmaxf(fmaxf(m0, m1), fmaxf(m2, m3)));
        }
        mloc = fmaxf(mloc, __shfl_xor(mloc, 32));

        float m_new = fmaxf(m_run, mloc);   // finite from chunk 0 (region 0 open)
        float alpha = __expf(m_run - m_new);
        float lloc = 0.f;
        #pragma unroll
        for (int t = 0; t < 5; ++t) {
            float s0 = 0.f, s1 = 0.f, s2 = 0.f, s3 = 0.f;
            #pragma unroll
            for (int g = 0; g < 4; ++g) {
                float p0 = __expf(acc[t][4 * g]     - m_new);
                float p1 = __expf(acc[t][4 * g + 1] - m_new);
                float p2 = __expf(acc[t][4 * g + 2] - m_new);
                float p3 = __expf(acc[t][4 * g + 3] - m_new);
                acc[t][4 * g] = p0; acc[t][4 * g + 1] = p1;
                acc[t][4 * g + 2] = p2; acc[t][4 * g + 3] = p3;
                s0 += p0; s1 += p1; s2 += p2; s3 += p3;
            }
            lloc += (s0 + s1) + (s2 + s3);
        }
        lloc += __shfl_xor(lloc, 32);
        l_run = l_run * alpha + lloc;
        m_run = m_new;
        #pragma unroll
        for (int j = 0; j < 16; ++j) { oacc[0][j] *= alpha; oacc[1][j] *= alpha; }

        // PV: out^T += V^T · P^T ; P^T via per-wave LDS bounce (b64 writes, b128 reads)
        #pragma unroll
        for (int t = 0; t < 5; ++t) {
            #pragma unroll
            for (int g = 0; g < 4; ++g) {
                unsigned u0 = pk2bf(acc[t][4 * g],     acc[t][4 * g + 1]);
                unsigned u1 = pk2bf(acc[t][4 * g + 2], acc[t][4 * g + 3]);
                // kcols 8g+4half .. +3 of this 32-tile, row = qrow (l31)
                *(uint2*)&Pb[wave][l31][8 * g + 4 * half] = make_uint2(u0, u1);
            }
            // same-wave in-order DS: write-then-read, no barrier (R2/R7/R8-proven)
            #pragma unroll
            for (int ks2 = 0; ks2 < 2; ++ks2) {
                short8 pb = *(const short8*)&Pb[wave][l31][ks2 * 16 + half * 8];
                int kc16 = (ch * 5 + t) * 2 + ks2;
                int cc = kc16 * 2 + half;
                #pragma unroll
                for (int mt = 0; mt < 2; ++mt) {
                    int vrow = 32 * mt + l31;
                    int swz = (cc & ~7) | ((cc ^ (vrow & 7)) & 7);
                    short8 va = *(const short8*)&KV[VBASE + vrow * VSTRU + (swz << 3)];
                    oacc[mt] = __builtin_amdgcn_mfma_f32_32x32x16_bf16(va, pb, oacc[mt], 0, 0, 0);
                }
            }
        }
    }

    // ---- normalize + store out^T C-layout: dh = 32mt + 8g + 4half + r ----
    const float inv = 1.0f / l_run;
    float* o = op + (size_t)qrow * INNER;
    #pragma unroll
    for (int mt = 0; mt < 2; ++mt) {
        #pragma unroll
        for (int g = 0; g < 4; ++g) {
            float4 ov;
            ov.x = oacc[mt][4 * g]     * inv;
            ov.y = oacc[mt][4 * g + 1] * inv;
            ov.z = oacc[mt][4 * g + 2] * inv;
            ov.w = oacc[mt][4 * g + 3] * inv;
            *(float4*)&o[32 * mt + 8 * g + 4 * half] = ov;
        }
    }
}

extern "C" void kernel_launch(void* const* d_in, const int* in_sizes, int n_in,
                              void* d_out, int out_size, void* d_ws, size_t ws_size,
                              hipStream_t stream) {
    const float* q  = (const float*)d_in[0];
    const float* k  = (const float*)d_in[1];
    const float* v  = (const float*)d_in[2];
    const float* dd = (const float*)d_in[3];
    float* out = (float*)d_out;
    dd_attn_kernel<<<dim3(256), dim3(512), 0, stream>>>(q, k, v, dd, out);
}